// Round 4
// baseline (188.529 us; speedup 1.0000x reference)
//
#include <hip/hip_runtime.h>
#include <hip/hip_bf16.h>

// Problem constants (match reference setup_inputs)
#define BB   64
#define CIN  2048
#define COUT 2048
#define TT   128

typedef int i32x4 __attribute__((ext_vector_type(4)));

__device__ __forceinline__ void async16(char* lds_dst, const char* g_src) {
    __builtin_amdgcn_global_load_lds(
        (const __attribute__((address_space(1))) void*)g_src,
        (__attribute__((address_space(3))) void*)lds_dst,
        16, 0, 0);
}

// --- Fused prep: masked weights -> i8 [COUT][CIN], spikes -> i8 A[(b*T+t)][c]
__global__ void prep_kernel(const float* __restrict__ spikes,
                            const float* __restrict__ w,
                            const float* __restrict__ msk,
                            char* __restrict__ A,
                            char* __restrict__ Wm) {
    __shared__ float tile[64][33];
    int bid = blockIdx.x;
    int tid = threadIdx.x;

    if (bid < 1024) {
        // weights: 16 elements/thread, exact int8 cast of w*mask
        size_t i = ((size_t)bid * 256 + tid) * 16;
        int out4[4];
#pragma unroll
        for (int q = 0; q < 4; ++q) {
            float4 a = *(const float4*)(w + i + q * 4);
            float4 m = *(const float4*)(msk + i + q * 4);
            int b0 = (int)(char)(int)(a.x * m.x);
            int b1 = (int)(char)(int)(a.y * m.y);
            int b2 = (int)(char)(int)(a.z * m.z);
            int b3 = (int)(char)(int)(a.w * m.w);
            out4[q] = (b0 & 0xFF) | ((b1 & 0xFF) << 8) | ((b2 & 0xFF) << 16) | (b3 << 24);
        }
        *(int4*)(Wm + i) = *(int4*)out4;
        return;
    }

    // spikes [B][C][T] fp32 -> A[(b*T+t)][c] i8 via LDS transpose
    bid -= 1024;
    int cc = bid & 31;          // c-tile: 64 channels
    int tt = (bid >> 5) & 3;    // t-tile: 32 timesteps
    int b  = bid >> 7;
    int c0 = cc * 64, t0 = tt * 32;

    // float4 reads: 8 lanes cover one 128-B channel row; wave = 8 rows
    int t4 = tid & 7;           // float4 slot along t
    int cr = tid >> 3;          // 0..31
#pragma unroll
    for (int s = 0; s < 2; ++s) {
        int c = cr + s * 32;
        float4 v = *(const float4*)(spikes + ((size_t)b * CIN + c0 + c) * TT + t0 + t4 * 4);
        tile[c][t4 * 4 + 0] = v.x;
        tile[c][t4 * 4 + 1] = v.y;
        tile[c][t4 * 4 + 2] = v.z;
        tile[c][t4 * 4 + 3] = v.w;
    }
    __syncthreads();

    int tw_ = tid >> 4;         // 0..15
    int cq  = tid & 15;
#pragma unroll
    for (int s2 = 0; s2 < 2; ++s2) {
        int tw = tw_ + s2 * 16;
        int packed = 0;
#pragma unroll
        for (int q = 0; q < 4; ++q)
            packed |= ((tile[cq * 4 + q][tw] != 0.f) ? 1 : 0) << (8 * q);
        *(int*)(A + ((size_t)(b * TT) + t0 + tw) * CIN + c0 + cq * 4) = packed;
    }
}

// --- Fused GEMM (128x128 tile, BK=64 double-buffered, mfma_i32_16x16x64_i8)
//     one barrier per K-iter, per-block K-rotation; LIF scan epilogue ---
__global__ void __launch_bounds__(256, 4)
snn_gemm_scan(const char* __restrict__ A,    // [8192][2048] i8
              const char* __restrict__ Wm,   // [2048][2048] i8
              const int* __restrict__ scale_exp,
              const int* __restrict__ thr_exp,
              float* __restrict__ out) {     // [B][COUT][T]
    __shared__ __align__(16) union {
        struct { char a[2][128 * 64]; char b[2][128 * 64]; } st;  // 32 KB dbuf
        float c[128 * 68];                                        // 34.8 KB
    } lds;
    __shared__ unsigned pb[64 * 4];

    const int tid  = threadIdx.x;
    const int lane = tid & 63;
    const int w    = tid >> 6;

    // XCD-aware swizzle: blocks on one XCD share b -> A-tile L2 reuse
    int flat = blockIdx.x;
    int xcd = flat & 7, idx = flat >> 3;
    int b  = xcd * 8 + (idx >> 4);
    int n0 = (idx & 15) * 128;
    int m0 = b * TT;

    // staging: window = 128 rows x 64 B = 4 chunks/row; 512 chunks per operand;
    // thread stages chunk ids {tid, tid+256}. Global col XOR-swizzled by row&3
    // (LDS placement stays linear per global_load_lds constraint).
    int rA = tid >> 2;                    // row 0..63 (second chunk: +64)
    int cA = (tid & 3) ^ (rA & 3);        // swizzled global chunk col (64%4==0)
    const char* gA0 = A  + (size_t)(m0 + rA) * CIN + cA * 16;
    const char* gA1 = gA0 + (size_t)64 * CIN;
    const char* gB0 = Wm + (size_t)(n0 + rA) * CIN + cA * 16;
    const char* gB1 = gB0 + (size_t)64 * CIN;
    char* sA = (char*)lds.st.a;           // [2][8192]
    char* sB = (char*)lds.st.b;

    // fragment byte offsets: A[m=lane&15][k=(lane>>4)*16..+16], pitch 4 chunks
    const int wm = (w >> 1) * 64, wn = (w & 1) * 64;
    const int mrow = lane & 15, kc = lane >> 4;
    unsigned offA[4], offB[4];
#pragma unroll
    for (int i = 0; i < 4; ++i) {
        offA[i] = (unsigned)(((wm + i * 16 + mrow) * 4 + (kc ^ (mrow & 3))) * 16);
        offB[i] = (unsigned)(((wn + i * 16 + mrow) * 4 + (kc ^ (mrow & 3))) * 16);
    }

    const int krot = flat & 31;           // decorrelate K start per block

    // preload window 0 into buffer 0
    {
        int k = ((krot) & 31) << 6;
        async16(sA + tid * 16,         gA0 + k);
        async16(sA + (tid + 256) * 16, gA1 + k);
        async16(sB + tid * 16,         gB0 + k);
        async16(sB + (tid + 256) * 16, gB1 + k);
    }

    i32x4 acc[4][4] = {};
    for (int i = 0; i < 32; ++i) {
        __syncthreads();  // drains window-i loads (issued last iter, ~full
                          // MFMA phase in flight) + guards buf (i+1)&1 reuse
        if (i < 31) {
            int k = ((i + 1 + krot) & 31) << 6;
            unsigned nb = (unsigned)(((i + 1) & 1) * 8192);
            async16(sA + nb + tid * 16,         gA0 + k);
            async16(sA + nb + (tid + 256) * 16, gA1 + k);
            async16(sB + nb + tid * 16,         gB0 + k);
            async16(sB + nb + (tid + 256) * 16, gB1 + k);
        }
        const char* bufA = sA + (unsigned)((i & 1) * 8192);
        const char* bufB = sB + (unsigned)((i & 1) * 8192);
        i32x4 av[4], bv[4];
#pragma unroll
        for (int ii = 0; ii < 4; ++ii) av[ii] = *(const i32x4*)(bufA + offA[ii]);
#pragma unroll
        for (int jj = 0; jj < 4; ++jj) bv[jj] = *(const i32x4*)(bufB + offB[jj]);
#pragma unroll
        for (int ii = 0; ii < 4; ++ii)
#pragma unroll
            for (int jj = 0; jj < 4; ++jj)
                acc[ii][jj] = __builtin_amdgcn_mfma_i32_16x16x64_i8(
                    av[ii], bv[jj], acc[ii][jj], 0, 0, 0);
    }

    const float thr = exp2f((float)thr_exp[0]);

    // Epilogue: two passes of 64 channels (LDS union stays ~35 KB -> 4 blk/CU)
#pragma unroll
    for (int p = 0; p < 2; ++p) {
        __syncthreads();
        if ((w & 1) == p) {
            const int rb = (lane >> 4) * 4;
            const int cb = lane & 15;
#pragma unroll
            for (int i = 0; i < 4; ++i)
#pragma unroll
                for (int j = 0; j < 4; ++j)
#pragma unroll
                    for (int r = 0; r < 4; ++r)
                        lds.c[(wm + i * 16 + rb + r) * 68 + (j * 16 + cb)] =
                            (float)acc[i][j][r];
        }
        __syncthreads();

        if (tid < 64) {
            float scale = exp2f((float)scale_exp[n0 + p * 64 + tid]);
            float a = 0.f;
            unsigned bits[4] = {0u, 0u, 0u, 0u};
#pragma unroll 4
            for (int t = 0; t < 128; ++t) {
                a += lds.c[t * 68 + tid] * scale;
                unsigned s = (a >= thr) ? 1u : 0u;
                if (s) a = 0.f;
                bits[t >> 5] |= s << (t & 31);
            }
#pragma unroll
            for (int q = 0; q < 4; ++q) pb[tid * 4 + q] = bits[q];
        }
        __syncthreads();

        // coalesced float4 stores: out[b][n0 + p*64 + co][t]
        const int t4 = tid & 31, cr = tid >> 5;
#pragma unroll
        for (int s2 = 0; s2 < 8; ++s2) {
            int co = s2 * 8 + cr;
            unsigned wb  = pb[co * 4 + (t4 >> 3)];
            unsigned nib = (wb >> ((t4 & 7) * 4)) & 0xFu;
            float4 v;
            v.x = (float)(nib & 1u);
            v.y = (float)((nib >> 1) & 1u);
            v.z = (float)((nib >> 2) & 1u);
            v.w = (float)((nib >> 3) & 1u);
            *(float4*)(out + (size_t)(b * COUT + n0 + p * 64 + co) * TT + t4 * 4) = v;
        }
    }
}

extern "C" void kernel_launch(void* const* d_in, const int* in_sizes, int n_in,
                              void* d_out, int out_size, void* d_ws, size_t ws_size,
                              hipStream_t stream) {
    const float* spikes  = (const float*)d_in[0];
    const float* weights = (const float*)d_in[1];
    const float* mask    = (const float*)d_in[2];
    const int*   scale_e = (const int*)d_in[3];
    const int*   thr_e   = (const int*)d_in[4];
    float* out = (float*)d_out;

    // workspace: A i8 [8192][2048] = 16 MB, Wm i8 [2048][2048] = 4 MB
    char* Ai8 = (char*)d_ws;
    char* Wm  = (char*)d_ws + (size_t)BB * TT * CIN;

    prep_kernel<<<1024 + BB * 4 * 32, 256, 0, stream>>>(spikes, weights, mask, Ai8, Wm);
    snn_gemm_scan<<<BB * (COUT / 128), 256, 0, stream>>>(Ai8, Wm, scale_e, thr_e, out);
}